// Round 10
// baseline (697.301 us; speedup 1.0000x reference)
//
#include <hip/hip_runtime.h>
#include <math.h>

// ---------------------------------------------------------------------------
// MuellerMatrixPyramid, fp32, MI355X.  5-dispatch DAG:
//   conv0 (48->48, 512^2) -> y0 (+fused shfl 4x4 maxpool -> x1)
//   conv1 (48->48, 128^2) -> y1
//   mm_both: y0 -> m0 AND y1 -> m1, one dispatch
//   up    (m1 -> u, bicubic a=-0.75 align_corners f32, 128->512)
//   oconv_both: oconv0(m0 -> out[:,0:17]) AND oconv1(u -> out[:,17:34])
//
// R10: conv staging via __builtin_amdgcn_global_load_lds (async HBM->LDS,
// no VGPR round-trip, no ds_writes). Per-row issue: dest = wave-uniform
// &buf[r*STRIDE] + lane*4 (m104 constraint). Border halo cells are
// channel-invariant -> zeroed ONCE into both buffers; masked lanes leave
// zeros intact => staged values bitwise identical to R9. Compute/FMA order
// untouched. Staging regs 27 -> ~7 (away from the cliff).
//
// HARD-WON RULES (R3-R9 post-mortems):
//  - 128-VGPR CLIFF: hipcc refuses to allocate past 128; excess live set
//    SPILLS acc to scratch (R5/R6: VGPR=128, 5.8 GB/dispatch, 4x slowdown).
//  - s_load weights in hot loop are POISON (SMEM shares lgkmcnt with DS,
//    out-of-order returns force lgkmcnt(0) drains). Weights stay in LDS.
//  - XCD remap of g to fastest blockIdx.x is WRONG (R3). g stays in z.
//  - Pool epilogue must be barrier-free (shfl_xor) (R7 vs R8).
//  - mm stays DOUBLE (cond ~1e4 pixels amplify inverse rounding).
//  - conv0 dur has ~+/-20us session variance (R8 352 vs R9 375, same code).
// ---------------------------------------------------------------------------

__device__ __forceinline__ float leakyf(float t) { return t >= 0.0f ? t : 0.01f * t; }

__device__ __forceinline__ void gload_lds4(const float* g, float* l)
{
    __builtin_amdgcn_global_load_lds(
        (const __attribute__((address_space(1))) void*)g,
        (__attribute__((address_space(3))) void*)l, 4, 0, 0);
}

// STAGE_CH: advance sbase one channel, async-load all rows this wave owns.
// LDS dest wave-uniform (wv,i,cb static or wave-uniform); global src per-lane.
// Masked lanes (row/col OOB) skip -> prologue zeros remain.
#define STAGE_CH(BUF)                                                         \
    {                                                                         \
        sbase += HW;                                                          \
        float* buf_ = (BUF);                                                  \
        _Pragma("unroll")                                                     \
        for (int i_ = 0; i_ < RPW; ++i_) {                                    \
            if (rvmask & (1u << i_)) {                                        \
                const float* rp_ = sbase + (size_t)(wv + 4 * i_) * W;         \
                _Pragma("unroll")                                             \
                for (int cb_ = 0; cb_ < COLS; cb_ += 64) {                    \
                    if (cok[cb_ / 64])                                        \
                        gload_lds4(rp_ + cb_ + lane,                          \
                                   &buf_[(wv + 4 * i_) * STRIDE + cb_]);      \
                }                                                             \
            }                                                                 \
        }                                                                     \
    }

// 256 threads = XG x-groups * TH rows; each thread PX px * OCPT out-channels.
// grid.z = B * NG  (TWO_SRC: plus second instance above z_split).
template<int CIN, int OCPT, int PX, int TW, bool DO_POOL, bool TWO_SRC>
__global__ __launch_bounds__(256, 2)
void conv3x3_leaky(const float* __restrict__ in, const float* __restrict__ wgt,
                   const float* __restrict__ bias, float* __restrict__ out,
                   float* __restrict__ pool_out,
                   int H, int W, int COUT, int NG,
                   int in_bstride, int out_bstride, int out_coff,
                   const float* __restrict__ in2, const float* __restrict__ wgt2,
                   const float* __restrict__ bias2, int coff2, int z_split)
{
    constexpr int XG     = TW / PX;
    constexpr int TH     = 256 / XG;
    constexpr int COLS   = TW + 2;
    constexpr int ROWS   = TH + 2;
    constexpr int STRIDE = (COLS + 3) & ~3;   // 16B-aligned rows
    constexpr int TSZ    = ROWS * STRIDE;
    constexpr int ELEMS  = ROWS * COLS;
    constexpr int NV     = PX + 2;
    constexpr int RPW    = (ROWS + 3) / 4;    // max rows per wave

    __shared__ float tile[2 * TSZ];           // double buffer
    __shared__ float wlds[CIN * OCPT * 12];   // all weights, staged once
    __shared__ float blds[OCPT];

    // instance select (block-uniform; folds away when !TWO_SRC)
    const float* insel = in;
    const float* wsel  = wgt;
    const float* bsel  = bias;
    int coff = out_coff;
    int bz   = blockIdx.z;
    if (TWO_SRC && bz >= z_split) {
        bz -= z_split;
        insel = in2; wsel = wgt2; bsel = bias2; coff = coff2;
    }

    const int tid   = threadIdx.x;
    const int lane  = tid & 63;
    const int wv    = tid >> 6;
    const int tx    = tid & (XG - 1);
    const int ty    = tid / XG;
    const int g     = bz % NG;
    const int b     = bz / NG;
    const int obase = g * OCPT;
    const int row0  = blockIdx.y * TH;
    const int col0  = blockIdx.x * TW;
    const int HW    = H * W;

    // stage ALL weights once: wlds[c][o][k], k padded to 12
    for (int idx = tid; idx < CIN * OCPT * 9; idx += 256) {
        int c  = idx / (OCPT * 9);
        int r2 = idx - c * (OCPT * 9);
        int o  = r2 / 9;
        int k2 = r2 - o * 9;
        int og = obase + o;
        wlds[(c * OCPT + o) * 12 + k2] = (og < COUT) ? wsel[(og * CIN + c) * 9 + k2] : 0.0f;
    }
    if (tid < OCPT) {
        int og = obase + tid;
        blds[tid] = (og < COUT) ? bsel[og] : 0.0f;
    }

    // zero never-loaded halo slots (channel-invariant), BOTH buffers, once
    for (int idx = tid; idx < ELEMS; idx += 256) {
        int r  = idx / COLS;
        int cc = idx - r * COLS;
        int gr = row0 - 1 + r;
        int gc = col0 - 1 + cc;
        if (!(gr >= 0 && gr < H && gc >= 0 && gc < W)) {
            tile[r * STRIDE + cc] = 0.0f;
            tile[TSZ + r * STRIDE + cc] = 0.0f;
        }
    }

    // staging state: column masks (loop-invariant), row-valid mask, base ptr
    bool cok[(COLS + 63) / 64];
#pragma unroll
    for (int j = 0; j < (COLS + 63) / 64; ++j) {
        int cc = j * 64 + lane;
        int gc = col0 - 1 + cc;
        cok[j] = (cc < COLS) && (gc >= 0) && (gc < W);
    }
    unsigned rvmask = 0;
#pragma unroll
    for (int i = 0; i < RPW; ++i) {
        int r  = wv + 4 * i;
        int gr = row0 - 1 + r;
        if (r < ROWS && gr >= 0 && gr < H) rvmask |= (1u << i);
    }
    const float* inb = insel + (size_t)b * in_bstride;
    const float* sbase = inb + (size_t)(row0 - 1) * W + (col0 - 1) - HW;

    // prologue: stage channel 0 into buffer 0 (async), then barrier (drains vmcnt)
    STAGE_CH(&tile[0]);
    __syncthreads();

    float acc[OCPT][PX];
#pragma unroll
    for (int o = 0; o < OCPT; ++o)
#pragma unroll
        for (int p = 0; p < PX; ++p) acc[o][p] = 0.0f;

    for (int c = 0; c < CIN; ++c) {
        // issue next channel's async loads into the other buffer
        if (c + 1 < CIN) STAGE_CH(&tile[((c + 1) & 1) * TSZ]);

        // compute channel c from buffer (c&1)  (unchanged FMA order)
        {
            const float* tb = &tile[(c & 1) * TSZ];
            float v[3][NV];
#pragma unroll
            for (int rr = 0; rr < 3; ++rr) {
                const float* tp = tb + (ty + rr) * STRIDE + tx * PX;
                float4 a0 = *(const float4*)tp;
                v[rr][0] = a0.x; v[rr][1] = a0.y; v[rr][2] = a0.z; v[rr][3] = a0.w;
                if constexpr (PX == 8) {
                    float4 a1 = *(const float4*)(tp + 4);
                    float2 a2 = *(const float2*)(tp + 8);
                    v[rr][4] = a1.x; v[rr][5] = a1.y; v[rr][6] = a1.z; v[rr][7] = a1.w;
                    v[rr][8] = a2.x; v[rr][9] = a2.y;
                } else {
                    float2 a1 = *(const float2*)(tp + 4);
                    v[rr][4] = a1.x; v[rr][5] = a1.y;
                }
            }
#pragma unroll
            for (int o = 0; o < OCPT; ++o) {
                const float* wp = &wlds[(c * OCPT + o) * 12];
                float4 w0 = *(const float4*)wp;
                float4 w1 = *(const float4*)(wp + 4);
                float w8 = wp[8];
                float wk[9] = {w0.x, w0.y, w0.z, w0.w, w1.x, w1.y, w1.z, w1.w, w8};
#pragma unroll
                for (int px = 0; px < PX; ++px) {
                    float s = acc[o][px];
#pragma unroll
                    for (int kr = 0; kr < 3; ++kr)
#pragma unroll
                        for (int kc = 0; kc < 3; ++kc)
                            s = fmaf(wk[kr * 3 + kc], v[kr][px + kc], s);
                    acc[o][px] = s;
                }
            }
        }

        // barrier: all compute(c) reads done + next channel's loads drained
        if (c + 1 < CIN) __syncthreads();   // uniform branch -> legal
    }

    const int orow = row0 + ty;
    float* outb = out + (size_t)b * out_bstride;
#pragma unroll
    for (int o = 0; o < OCPT; ++o) {
        int og = obase + o;
        if (og < COUT) {
            float bv = blds[o];
            float r[PX];
#pragma unroll
            for (int p = 0; p < PX; ++p) { float t = acc[o][p] + bv; r[p] = leakyf(t); }
            float* op = outb + ((coff + og) * H + orow) * W + col0 + tx * PX;
#pragma unroll
            for (int q = 0; q < PX / 4; ++q)
                *(float4*)(op + 4 * q) = make_float4(r[4*q], r[4*q+1], r[4*q+2], r[4*q+3]);
        }
    }

    // ---- fused 4x4 maxpool (conv0 only): shfl_xor reduction, NO barriers ----
    if constexpr (DO_POOL) {
        static_assert(PX == 8 && XG == 8, "pool fusion assumes PX=8, XG=8");
        const int pH = H >> 2, pW = W >> 2;
        const int prow = (row0 + ty) >> 2;          // meaningful when ty%4==0
        const int pcol = (col0 >> 2) + tx * 2;
        const bool writer = (ty & 3) == 0;
#pragma unroll
        for (int o = 0; o < OCPT; ++o) {
            float bv = blds[o];
            float c0 = leakyf(acc[o][0] + bv);
            c0 = fmaxf(c0, leakyf(acc[o][1] + bv));
            c0 = fmaxf(c0, leakyf(acc[o][2] + bv));
            c0 = fmaxf(c0, leakyf(acc[o][3] + bv));
            float c1 = leakyf(acc[o][4] + bv);
            c1 = fmaxf(c1, leakyf(acc[o][5] + bv));
            c1 = fmaxf(c1, leakyf(acc[o][6] + bv));
            c1 = fmaxf(c1, leakyf(acc[o][7] + bv));
            c0 = fmaxf(c0, __shfl_xor(c0, 8));
            c0 = fmaxf(c0, __shfl_xor(c0, 16));
            c1 = fmaxf(c1, __shfl_xor(c1, 8));
            c1 = fmaxf(c1, __shfl_xor(c1, 16));
            if (writer) {
                int og = obase + o;
                *(float2*)(pool_out + ((size_t)(b * COUT + og) * pH + prow) * pW + pcol)
                    = make_float2(c0, c1);
            }
        }
    }
}

#undef STAGE_CH

// ---------------- 4x4 inverse (double, adjugate) ---------------------------
__device__ __forceinline__ void inv4x4(const double* m, double* invOut)
{
    double inv[16];
    inv[0]  =  m[5]*m[10]*m[15] - m[5]*m[11]*m[14] - m[9]*m[6]*m[15] + m[9]*m[7]*m[14] + m[13]*m[6]*m[11] - m[13]*m[7]*m[10];
    inv[4]  = -m[4]*m[10]*m[15] + m[4]*m[11]*m[14] + m[8]*m[6]*m[15] - m[8]*m[7]*m[14] - m[12]*m[6]*m[11] + m[12]*m[7]*m[10];
    inv[8]  =  m[4]*m[9]*m[15]  - m[4]*m[11]*m[13] - m[8]*m[5]*m[15] + m[8]*m[7]*m[13] + m[12]*m[5]*m[11] - m[12]*m[7]*m[9];
    inv[12] = -m[4]*m[9]*m[14]  + m[4]*m[10]*m[13] + m[8]*m[5]*m[14] - m[8]*m[6]*m[13] - m[12]*m[5]*m[10] + m[12]*m[6]*m[9];
    inv[1]  = -m[1]*m[10]*m[15] + m[1]*m[11]*m[14] + m[9]*m[2]*m[15] - m[9]*m[3]*m[14] - m[13]*m[2]*m[11] + m[13]*m[3]*m[10];
    inv[5]  =  m[0]*m[10]*m[15] - m[0]*m[11]*m[14] - m[8]*m[2]*m[15] + m[8]*m[3]*m[14] + m[12]*m[2]*m[11] - m[12]*m[3]*m[10];
    inv[9]  = -m[0]*m[9]*m[15]  + m[0]*m[11]*m[13] + m[8]*m[1]*m[15] - m[8]*m[3]*m[13] - m[12]*m[1]*m[11] + m[12]*m[3]*m[9];
    inv[13] =  m[0]*m[9]*m[14]  - m[0]*m[10]*m[13] - m[8]*m[1]*m[14] + m[8]*m[2]*m[13] + m[12]*m[1]*m[10] - m[12]*m[2]*m[9];
    inv[2]  =  m[1]*m[6]*m[15]  - m[1]*m[7]*m[14]  - m[5]*m[2]*m[15] + m[5]*m[3]*m[14] + m[13]*m[2]*m[7]  - m[13]*m[3]*m[6];
    inv[6]  = -m[0]*m[6]*m[15]  + m[0]*m[7]*m[14]  + m[4]*m[2]*m[15] - m[4]*m[3]*m[14] - m[12]*m[2]*m[7]  + m[12]*m[3]*m[6];
    inv[10] =  m[0]*m[5]*m[15]  - m[0]*m[7]*m[13]  - m[4]*m[1]*m[15] + m[4]*m[3]*m[13] + m[12]*m[1]*m[7]  - m[12]*m[3]*m[5];
    inv[14] = -m[0]*m[5]*m[14]  + m[0]*m[6]*m[13]  + m[4]*m[1]*m[14] - m[4]*m[2]*m[13] - m[12]*m[1]*m[6]  + m[12]*m[2]*m[5];
    inv[3]  = -m[1]*m[6]*m[11]  + m[1]*m[7]*m[10]  + m[5]*m[2]*m[11] - m[5]*m[3]*m[10] - m[9]*m[2]*m[7]   + m[9]*m[3]*m[6];
    inv[7]  =  m[0]*m[6]*m[11]  - m[0]*m[7]*m[10]  - m[4]*m[2]*m[11] + m[4]*m[3]*m[10] + m[8]*m[2]*m[7]   - m[8]*m[3]*m[6];
    inv[11] = -m[0]*m[5]*m[11]  + m[0]*m[7]*m[9]   + m[4]*m[1]*m[11] - m[4]*m[3]*m[9]  - m[8]*m[1]*m[7]   + m[8]*m[3]*m[5];
    inv[15] =  m[0]*m[5]*m[10]  - m[0]*m[6]*m[9]   - m[4]*m[1]*m[10] + m[4]*m[2]*m[9]  + m[8]*m[1]*m[6]   - m[8]*m[2]*m[5];
    double det = m[0]*inv[0] + m[1]*inv[4] + m[2]*inv[8] + m[3]*inv[12];
    det = 1.0 / det;
#pragma unroll
    for (int i = 0; i < 16; ++i) invOut[i] = inv[i] * det;
}

__device__ __forceinline__ void matmul4(const double* A, const double* B, double* C)
{
#pragma unroll
    for (int r = 0; r < 4; ++r)
#pragma unroll
        for (int c = 0; c < 4; ++c) {
            double s = 0.0;
#pragma unroll
            for (int k = 0; k < 4; ++k) s += A[r * 4 + k] * B[k * 4 + c];
            C[r * 4 + c] = s;
        }
}

// ---------------- mm_features, both pyramid levels in one dispatch ---------
__global__ __launch_bounds__(256)
void mm_features_kernel(const float* __restrict__ y0, float* __restrict__ m0,
                        int HW0, int n0,
                        const float* __restrict__ y1, float* __restrict__ m1,
                        int HW1, int ntot)
{
    int p = blockIdx.x * 256 + threadIdx.x;
    if (p >= ntot) return;
    const float* y; float* mo; int HW;
    if (p < n0) { y = y0; mo = m0; HW = HW0; }
    else        { p -= n0; y = y1; mo = m1; HW = HW1; }
    int b  = p / HW;
    int sp = p - b * HW;
    const float* base = y + (size_t)b * 48 * HW + sp;

    double A[16];
#pragma unroll
    for (int i = 0; i < 16; ++i) {
        double e = (i == 0 || i == 5 || i == 10 || i == 15) ? 1e-4 : 0.0;
        A[i] = (double)base[(16 + i) * HW] + e;
    }
    double iA[16];
    inv4x4(A, iA);                     // A dead

    double F[16];
    double s = 0.0;
#pragma unroll
    for (int i = 0; i < 16; ++i) { F[i] = (double)base[i * HW]; }
#pragma unroll
    for (int i = 0; i < 16; ++i) s += F[i];
    s *= (1.0 / 16.0);

    double T[16];
    matmul4(iA, F, T);                 // iA, F dead

    double Wm[16];
#pragma unroll
    for (int i = 0; i < 16; ++i) {
        double e = (i == 0 || i == 5 || i == 10 || i == 15) ? 1e-4 : 0.0;
        Wm[i] = (double)base[(32 + i) * HW] + e;
    }
    double iW[16];
    inv4x4(Wm, iW);                    // Wm dead

    double M[16];
    matmul4(T, iW, M);

    float* ob = mo + (size_t)b * 17 * HW + sp;
    ob[0] = (float)s;
#pragma unroll
    for (int i = 0; i < 16; ++i) ob[(1 + i) * HW] = (float)M[i];
}

// ---------------- bicubic x4 upsample 128->512, align_corners, a=-0.75 -----
__device__ __forceinline__ float cubwf(float t)
{
    t = fabsf(t);
    if (t <= 1.0f) return (1.25f * t - 2.25f) * t * t + 1.0f;          // a=-0.75
    if (t < 2.0f)  return (((t - 5.0f) * t + 8.0f) * t - 4.0f) * -0.75f;
    return 0.0f;
}

__global__ __launch_bounds__(256)
void bicubic_up4_kernel(const float* __restrict__ src, float* __restrict__ dst, int n)
{
    int idx = blockIdx.x * 256 + threadIdx.x;
    if (idx >= n) return;
    int P  = idx & 511;
    int O  = (idx >> 9) & 511;
    int bc = idx >> 18;                 // b*17 + c
    const float scale = 127.0f / 511.0f;
    float sh = O * scale, sw = P * scale;
    int i0 = (int)floorf(sh), j0 = (int)floorf(sw);
    float wh[4], ww[4];
#pragma unroll
    for (int k = 0; k < 4; ++k) {
        wh[k] = cubwf(sh - (float)(i0 + k - 1));
        ww[k] = cubwf(sw - (float)(j0 + k - 1));
    }
    const float* sp = src + bc * 16384;
    float acc = 0.0f;
#pragma unroll
    for (int ki = 0; ki < 4; ++ki) {
        int ih = min(max(i0 - 1 + ki, 0), 127);
        float rs = 0.0f;
#pragma unroll
        for (int kj = 0; kj < 4; ++kj) {
            int iw = min(max(j0 - 1 + kj, 0), 127);
            rs = fmaf(ww[kj], sp[ih * 128 + iw], rs);
        }
        acc = fmaf(wh[ki], rs, acc);
    }
    dst[idx] = acc;
}

// ---------------------------------------------------------------------------
extern "C" void kernel_launch(void* const* d_in, const int* in_sizes, int n_in,
                              void* d_out, int out_size, void* d_ws, size_t ws_size,
                              hipStream_t stream)
{
    const float* x   = (const float*)d_in[0];
    const float* iW0 = (const float*)d_in[1];
    const float* iB0 = (const float*)d_in[2];
    const float* iW1 = (const float*)d_in[3];
    const float* iB1 = (const float*)d_in[4];
    const float* oW0 = (const float*)d_in[5];
    const float* oB0 = (const float*)d_in[6];
    const float* oW1 = (const float*)d_in[7];
    const float* oB1 = (const float*)d_in[8];
    float* out = (float*)d_out;
    float* ws  = (float*)d_ws;

    // workspace layout (floats)
    float* y0 = ws;                     //  2*48*512*512 = 25165824
    float* m0 = ws + 25165824;          //  2*17*512*512 =  8912896
    float* x1 = ws + 34078720;          //  2*48*128*128 =  1572864
    float* y1 = ws + 35651584;          //  1572864
    float* m1 = ws + 37224448;          //  2*17*128*128 =   557056
    float* u  = ws;                     //  reuse y0 region (y0 dead by then)

    // conv0 (maxpool fused via shfl -> x1)
    conv3x3_leaky<48, 8, 8, 64, true, false><<<dim3(8, 16, 12), 256, 0, stream>>>(
        x, iW0, iB0, y0, x1, 512, 512, 48, 6, 48 * 512 * 512, 48 * 512 * 512, 0,
        nullptr, nullptr, nullptr, 0, 0);

    // conv1 (128^2: 32x32 tiles, OCPT=4 -> 384 blocks)
    conv3x3_leaky<48, 4, 4, 32, false, false><<<dim3(4, 4, 24), 256, 0, stream>>>(
        x1, iW1, iB1, y1, nullptr, 128, 128, 48, 12, 48 * 128 * 128, 48 * 128 * 128, 0,
        nullptr, nullptr, nullptr, 0, 0);

    // mm for both levels: n0 = 2*512^2 (divisible by 256 -> block-uniform split)
    mm_features_kernel<<<(2 * 512 * 512 + 2 * 128 * 128) / 256, 256, 0, stream>>>(
        y0, m0, 512 * 512, 2 * 512 * 512, y1, m1, 128 * 128,
        2 * 512 * 512 + 2 * 128 * 128);

    // bicubic upsample (f32)
    bicubic_up4_kernel<<<(2 * 17 * 512 * 512) / 256, 256, 0, stream>>>(m1, u, 2 * 17 * 512 * 512);

    // oconv0 + oconv1 merged: z<4 -> (m0,oW0,oB0,coff 0); z>=4 -> (u,oW1,oB1,coff 17)
    conv3x3_leaky<17, 9, 8, 64, false, true><<<dim3(8, 16, 8), 256, 0, stream>>>(
        m0, oW0, oB0, out, nullptr, 512, 512, 17, 2, 17 * 512 * 512, 34 * 512 * 512, 0,
        u, oW1, oB1, 17, 4);
}